// Round 2
// baseline (839.299 us; speedup 1.0000x reference)
//
#include <hip/hip_runtime.h>

// SpMM: COO sparse A (16384x16384, 1,048,576 nnz) @ dense B (16384x256) -> out (16384x256)
// Baseline: wave-per-nonzero atomic scatter.
//   - Indices are INT32 (JAX default x64-disabled; harness passes int32), shape [2, NNZ]:
//     rows at [0,NNZ), cols at [NNZ, 2*NNZ).
//   - Each 64-lane wave owns one nonzero: loads row/col/val (wave-uniform),
//     reads B[col, :] coalesced (lane i -> cols i, i+64, i+128, i+192),
//     atomicAdd into out[row, :] with the same fully-coalesced pattern.
//   - out zero-initialized each call (harness poisons 0xAA, never re-poisons).

#define NNZ_C 1048576
#define NCOL 256

__global__ __launch_bounds__(256) void spmm_atomic_kernel(
    const float* __restrict__ vals,
    const int* __restrict__ idx,         // [2, NNZ] int32: rows then cols
    const float* __restrict__ B,
    float* __restrict__ out)
{
    const int wave = (int)(blockIdx.x * (blockDim.x >> 6) + (threadIdx.x >> 6));
    const int lane = (int)(threadIdx.x & 63);
    if (wave >= NNZ_C) return;

    const int r = idx[wave];             // wave-uniform
    const int c = idx[NNZ_C + wave];     // wave-uniform
    const float v = vals[wave];          // wave-uniform

    const float* __restrict__ brow = B + (size_t)c * NCOL;
    float* __restrict__ orow = out + (size_t)r * NCOL;

#pragma unroll
    for (int k = 0; k < 4; ++k) {
        const int col = lane + 64 * k;   // coalesced 256B/wave per access
        atomicAdd(&orow[col], v * brow[col]);
    }
}

extern "C" void kernel_launch(void* const* d_in, const int* in_sizes, int n_in,
                              void* d_out, int out_size, void* d_ws, size_t ws_size,
                              hipStream_t stream) {
    const float* A_values  = (const float*)d_in[0];
    const int*   A_indices = (const int*)d_in[1];   // int32! (JAX x64 disabled)
    const float* B         = (const float*)d_in[2];
    float*       out       = (float*)d_out;

    // Zero output (atomic accumulation target). hipMemsetAsync is graph-capturable.
    hipMemsetAsync(d_out, 0, (size_t)out_size * sizeof(float), stream);

    const int waves_per_block = 256 / 64;                       // 4 nnz per block
    const int nblocks = (NNZ_C + waves_per_block - 1) / waves_per_block;  // 262144
    spmm_atomic_kernel<<<nblocks, 256, 0, stream>>>(A_values, A_indices, B, out);
}

// Round 3
// 272.984 us; speedup vs baseline: 3.0745x; 3.0745x over previous
//
#include <hip/hip_runtime.h>
#include <stdint.h>

// SpMM: COO sparse A (16384x16384, 1,048,576 nnz) @ dense B (16384x256) -> out (16384x256)
// Strategy: on-device counting sort -> CSR, then wave-per-row register accumulation.
// No output atomics (round-2 counters showed 1.07 GB atomic write-through = the bottleneck).
//
// Phases (all on `stream`, graph-capturable):
//   0. memset counts[16384] = 0
//   1. histogram: counts[row]++  (int atomics, L2-resident)
//   2. single-block exclusive scan -> offsets[16385]; cursor[i] = offsets[i]
//   3. scatter: pairs[atomicAdd(cursor[row])] = (col, val)
//   4. spmm: wave r accumulates acc[4]/lane over pairs[offsets[r]..offsets[r+1]),
//      B row read as float4 (1 KB/wave coalesced), single float4 store per lane.
//      Rows with zero nnz store zeros -> d_out needs no separate clearing.

#define M_ROWS 16384
#define NNZ_C  1048576
#define NCOL   256

// ---------------- phase 1: histogram ----------------
__global__ __launch_bounds__(256) void hist_kernel(const int* __restrict__ idx,
                                                   unsigned int* __restrict__ counts) {
    int i = blockIdx.x * 256 + threadIdx.x;
    if (i < NNZ_C) atomicAdd(&counts[idx[i]], 1u);
}

// ---------------- phase 2: exclusive scan (single block, 1024 thr x 16 elems) ----------------
__global__ __launch_bounds__(1024) void scan_kernel(const unsigned int* __restrict__ counts,
                                                    unsigned int* __restrict__ offsets,
                                                    unsigned int* __restrict__ cursor) {
    __shared__ unsigned int lds[1024];
    const int t = threadIdx.x;
    unsigned int local[16];
    unsigned int sum = 0;
#pragma unroll
    for (int i = 0; i < 16; ++i) { local[i] = counts[t * 16 + i]; sum += local[i]; }
    lds[t] = sum;
    __syncthreads();
    // Hillis-Steele inclusive scan over 1024 partials
    for (int off = 1; off < 1024; off <<= 1) {
        unsigned int v = (t >= off) ? lds[t - off] : 0u;
        __syncthreads();
        lds[t] += v;
        __syncthreads();
    }
    unsigned int base = lds[t] - sum;  // exclusive base for this thread's chunk
#pragma unroll
    for (int i = 0; i < 16; ++i) {
        offsets[t * 16 + i] = base;
        cursor[t * 16 + i]  = base;   // cursor aliases counts buffer; reads done above
        base += local[i];
    }
    if (t == 1023) offsets[M_ROWS] = lds[1023];
}

// ---------------- phase 3: scatter into row-sorted order ----------------
__global__ __launch_bounds__(256) void scatter_kernel(const int* __restrict__ idx,
                                                      const float* __restrict__ vals,
                                                      unsigned int* __restrict__ cursor,
                                                      int2* __restrict__ pairs) {
    int i = blockIdx.x * 256 + threadIdx.x;
    if (i >= NNZ_C) return;
    int r = idx[i];
    int c = idx[NNZ_C + i];
    float v = vals[i];
    unsigned int pos = atomicAdd(&cursor[r], 1u);
    pairs[pos] = make_int2(c, __float_as_int(v));
}

// ---------------- phase 4: wave-per-row SpMM ----------------
__global__ __launch_bounds__(256) void spmm_csr_kernel(const unsigned int* __restrict__ offsets,
                                                       const int2* __restrict__ pairs,
                                                       const float* __restrict__ B,
                                                       float* __restrict__ out) {
    const int row  = blockIdx.x * 4 + (threadIdx.x >> 6);   // wave = row
    const int lane = threadIdx.x & 63;

    unsigned int beg = offsets[row];
    unsigned int end = offsets[row + 1];
    // force wave-uniform -> scalar loads for the pair stream
    beg = __builtin_amdgcn_readfirstlane(beg);
    end = __builtin_amdgcn_readfirstlane(end);

    const float4* __restrict__ B4 = (const float4*)B;
    float4 acc = make_float4(0.f, 0.f, 0.f, 0.f);

    for (unsigned int p = beg; p < end; ++p) {
        int2 cv = pairs[p];                         // wave-uniform (scalar-cached)
        float v = __int_as_float(cv.y);
        float4 b = B4[(size_t)cv.x * 64 + lane];    // coalesced 1KB/wave gather
        acc.x += v * b.x;
        acc.y += v * b.y;
        acc.z += v * b.z;
        acc.w += v * b.w;
    }
    ((float4*)out)[(size_t)row * 64 + lane] = acc;  // single coalesced 1KB/wave store
}

// ---------------- fallback (round-2 baseline) if workspace too small ----------------
__global__ __launch_bounds__(256) void spmm_atomic_kernel(
    const float* __restrict__ vals, const int* __restrict__ idx,
    const float* __restrict__ B, float* __restrict__ out) {
    const int wave = (int)(blockIdx.x * 4 + (threadIdx.x >> 6));
    const int lane = (int)(threadIdx.x & 63);
    if (wave >= NNZ_C) return;
    const int r = idx[wave];
    const int c = idx[NNZ_C + wave];
    const float v = vals[wave];
    const float* brow = B + (size_t)c * NCOL;
    float* orow = out + (size_t)r * NCOL;
#pragma unroll
    for (int k = 0; k < 4; ++k) {
        const int col = lane + 64 * k;
        atomicAdd(&orow[col], v * brow[col]);
    }
}

extern "C" void kernel_launch(void* const* d_in, const int* in_sizes, int n_in,
                              void* d_out, int out_size, void* d_ws, size_t ws_size,
                              hipStream_t stream) {
    const float* A_values  = (const float*)d_in[0];
    const int*   A_indices = (const int*)d_in[1];   // int32 (JAX x64 disabled), [2, NNZ]
    const float* B         = (const float*)d_in[2];
    float*       out       = (float*)d_out;

    // workspace layout
    const size_t OFFSETS_OFF = 0;                       // 16385 u32 = 65,540 B
    const size_t COUNTS_OFF  = 66560;                   // 16384 u32 = 65,536 B (reused as cursor)
    const size_t PAIRS_OFF   = COUNTS_OFF + 65536;      // 132,096 B (16B aligned)
    const size_t NEEDED      = PAIRS_OFF + (size_t)NNZ_C * 8;  // ~8.5 MB

    if (ws_size < NEEDED) {
        // fallback: atomic scatter baseline
        hipMemsetAsync(d_out, 0, (size_t)out_size * sizeof(float), stream);
        spmm_atomic_kernel<<<NNZ_C / 4, 256, 0, stream>>>(A_values, A_indices, B, out);
        return;
    }

    uint8_t* w = (uint8_t*)d_ws;
    unsigned int* offsets = (unsigned int*)(w + OFFSETS_OFF);
    unsigned int* counts  = (unsigned int*)(w + COUNTS_OFF);   // also cursor
    int2*         pairs   = (int2*)(w + PAIRS_OFF);

    hipMemsetAsync(counts, 0, M_ROWS * sizeof(unsigned int), stream);
    hist_kernel<<<NNZ_C / 256, 256, 0, stream>>>(A_indices, counts);
    scan_kernel<<<1, 1024, 0, stream>>>(counts, offsets, counts /*cursor*/);
    scatter_kernel<<<NNZ_C / 256, 256, 0, stream>>>(A_indices, A_values, counts /*cursor*/, pairs);
    spmm_csr_kernel<<<M_ROWS / 4, 256, 0, stream>>>(offsets, pairs, B, out);
}

// Round 4
// 268.250 us; speedup vs baseline: 3.1288x; 1.0176x over previous
//
#include <hip/hip_runtime.h>
#include <stdint.h>

// SpMM: COO sparse A (16384x16384, 1,048,576 nnz) @ dense B (16384x256) -> out (16384x256)
// CSR-build (counting sort) + wave-per-row SpMM.
// Round-4 change: spmm inner loop restructured for ILP — coalesced 64-pair chunk
// load + v_readlane broadcast, so all B-gather addresses in a chunk are known
// up-front and the compiler can pipeline gathers (was: serial scalar pair loads
// gating each 1KB gather; 123us latency-bound, VALUBusy 4.4%).

#define M_ROWS 16384
#define NNZ_C  1048576
#define NCOL   256

// ---------------- phase 1: histogram ----------------
__global__ __launch_bounds__(256) void hist_kernel(const int* __restrict__ idx,
                                                   unsigned int* __restrict__ counts) {
    int i = blockIdx.x * 256 + threadIdx.x;
    if (i < NNZ_C) atomicAdd(&counts[idx[i]], 1u);
}

// ---------------- phase 2: exclusive scan (single block, 1024 thr x 16 elems) ----------------
__global__ __launch_bounds__(1024) void scan_kernel(const unsigned int* __restrict__ counts,
                                                    unsigned int* __restrict__ offsets,
                                                    unsigned int* __restrict__ cursor) {
    __shared__ unsigned int lds[1024];
    const int t = threadIdx.x;
    unsigned int local[16];
    unsigned int sum = 0;
#pragma unroll
    for (int i = 0; i < 16; ++i) { local[i] = counts[t * 16 + i]; sum += local[i]; }
    lds[t] = sum;
    __syncthreads();
    for (int off = 1; off < 1024; off <<= 1) {
        unsigned int v = (t >= off) ? lds[t - off] : 0u;
        __syncthreads();
        lds[t] += v;
        __syncthreads();
    }
    unsigned int base = lds[t] - sum;  // exclusive base for this thread's chunk
#pragma unroll
    for (int i = 0; i < 16; ++i) {
        offsets[t * 16 + i] = base;
        cursor[t * 16 + i]  = base;
        base += local[i];
    }
    if (t == 1023) offsets[M_ROWS] = lds[1023];
}

// ---------------- phase 3: scatter into row-sorted order ----------------
__global__ __launch_bounds__(256) void scatter_kernel(const int* __restrict__ idx,
                                                      const float* __restrict__ vals,
                                                      unsigned int* __restrict__ cursor,
                                                      int2* __restrict__ pairs) {
    int i = blockIdx.x * 256 + threadIdx.x;
    if (i >= NNZ_C) return;
    int r = idx[i];
    int c = idx[NNZ_C + i];
    float v = vals[i];
    unsigned int pos = atomicAdd(&cursor[r], 1u);
    pairs[pos] = make_int2(c, __float_as_int(v));
}

// ---------------- phase 4: wave-per-row SpMM, chunked-ILP inner loop ----------------
__global__ __launch_bounds__(256) void spmm_csr_kernel(const unsigned int* __restrict__ offsets,
                                                       const int2* __restrict__ pairs,
                                                       const float* __restrict__ B,
                                                       float* __restrict__ out) {
    const int row  = blockIdx.x * 4 + (threadIdx.x >> 6);   // wave = row
    const int lane = threadIdx.x & 63;

    unsigned int beg = __builtin_amdgcn_readfirstlane(offsets[row]);
    unsigned int end = __builtin_amdgcn_readfirstlane(offsets[row + 1]);

    const float4* __restrict__ B4 = (const float4*)B;
    float4 acc = make_float4(0.f, 0.f, 0.f, 0.f);

    for (unsigned int base_p = beg; base_p < end; base_p += 64) {
        // one coalesced 512B load pulls 64 pairs into the wave's registers;
        // OOB lanes fabricate (col=0, val=0) -> contributes 0 via an L1-hot line
        const unsigned int p = base_p + lane;
        int pc = 0, pv = 0;
        if (p < end) {
            int2 pr = pairs[p];
            pc = pr.x;
            pv = pr.y;
        }
        const int n = (int)min(64u, end - base_p);
        (void)n;
#pragma unroll 8
        for (int j = 0; j < 64; ++j) {
            const int   c = __builtin_amdgcn_readlane(pc, j);          // SGPR col
            const float v = __int_as_float(__builtin_amdgcn_readlane(pv, j)); // SGPR val
            const float4 b = B4[(size_t)c * 64 + lane];                // 1KB/wave gather
            acc.x += v * b.x;
            acc.y += v * b.y;
            acc.z += v * b.z;
            acc.w += v * b.w;
        }
    }
    ((float4*)out)[(size_t)row * 64 + lane] = acc;  // single coalesced 1KB/wave store
}

// ---------------- fallback if workspace too small ----------------
__global__ __launch_bounds__(256) void spmm_atomic_kernel(
    const float* __restrict__ vals, const int* __restrict__ idx,
    const float* __restrict__ B, float* __restrict__ out) {
    const int wave = (int)(blockIdx.x * 4 + (threadIdx.x >> 6));
    const int lane = (int)(threadIdx.x & 63);
    if (wave >= NNZ_C) return;
    const int r = idx[wave];
    const int c = idx[NNZ_C + wave];
    const float v = vals[wave];
    const float* brow = B + (size_t)c * NCOL;
    float* orow = out + (size_t)r * NCOL;
#pragma unroll
    for (int k = 0; k < 4; ++k) {
        const int col = lane + 64 * k;
        atomicAdd(&orow[col], v * brow[col]);
    }
}

extern "C" void kernel_launch(void* const* d_in, const int* in_sizes, int n_in,
                              void* d_out, int out_size, void* d_ws, size_t ws_size,
                              hipStream_t stream) {
    const float* A_values  = (const float*)d_in[0];
    const int*   A_indices = (const int*)d_in[1];   // int32 (JAX x64 disabled), [2, NNZ]
    const float* B         = (const float*)d_in[2];
    float*       out       = (float*)d_out;

    const size_t OFFSETS_OFF = 0;                       // 16385 u32
    const size_t COUNTS_OFF  = 66560;                   // 16384 u32 (reused as cursor)
    const size_t PAIRS_OFF   = COUNTS_OFF + 65536;
    const size_t NEEDED      = PAIRS_OFF + (size_t)NNZ_C * 8;  // ~8.5 MB

    if (ws_size < NEEDED) {
        hipMemsetAsync(d_out, 0, (size_t)out_size * sizeof(float), stream);
        spmm_atomic_kernel<<<NNZ_C / 4, 256, 0, stream>>>(A_values, A_indices, B, out);
        return;
    }

    uint8_t* w = (uint8_t*)d_ws;
    unsigned int* offsets = (unsigned int*)(w + OFFSETS_OFF);
    unsigned int* counts  = (unsigned int*)(w + COUNTS_OFF);   // also cursor
    int2*         pairs   = (int2*)(w + PAIRS_OFF);

    hipMemsetAsync(counts, 0, M_ROWS * sizeof(unsigned int), stream);
    hist_kernel<<<NNZ_C / 256, 256, 0, stream>>>(A_indices, counts);
    scan_kernel<<<1, 1024, 0, stream>>>(counts, offsets, counts /*cursor*/);
    scatter_kernel<<<NNZ_C / 256, 256, 0, stream>>>(A_indices, A_values, counts /*cursor*/, pairs);
    spmm_csr_kernel<<<M_ROWS / 4, 256, 0, stream>>>(offsets, pairs, B, out);
}

// Round 5
// 255.251 us; speedup vs baseline: 3.2881x; 1.0509x over previous
//
#include <hip/hip_runtime.h>
#include <stdint.h>

// SpMM: COO sparse A (16384x16384, 1,048,576 nnz) @ dense B (16384x256) -> out (16384x256)
// CSR-build (counting sort) + wave-per-row SpMM.
//
// Round-5: setup vectorization. spmm is measured to sit at the vector-memory
// address-processing wall (~1 lane-addr/cy/CU: 1M nnz x 64 lane-addrs / 256 CU
// / 2.4GHz = 109us ~= observed 121us; cache/MLP restructures were no-ops), so
// it is left unchanged as a control. Setup (=total 268 - spmm 121 = 147us) is
// attacked: int4/float4 loads everywhere (4 nnz per thread), and the
// single-block scan's 16384 scalar cross-XCD loads (suspected ~80us, shallow
// MLP x ~600cy latency) become 4096 independent uint4 loads.

#define M_ROWS 16384
#define NNZ_C  1048576
#define NCOL   256

// ---------------- phase 1: histogram (4 nnz/thread via int4) ----------------
__global__ __launch_bounds__(256) void hist_kernel(const int* __restrict__ idx,
                                                   unsigned int* __restrict__ counts) {
    const int i = blockIdx.x * 256 + threadIdx.x;          // 262144 threads
    const int4 r4 = ((const int4*)idx)[i];                 // rows segment
    atomicAdd(&counts[r4.x], 1u);
    atomicAdd(&counts[r4.y], 1u);
    atomicAdd(&counts[r4.z], 1u);
    atomicAdd(&counts[r4.w], 1u);
}

// ---------------- phase 2: exclusive scan (1 block, 1024 thr x 16 bins) ----------------
__global__ __launch_bounds__(1024) void scan_kernel(const unsigned int* __restrict__ counts,
                                                    unsigned int* __restrict__ offsets,
                                                    unsigned int* __restrict__ cursor) {
    __shared__ unsigned int lds[1024];
    const int t = threadIdx.x;

    // 4 independent uint4 loads per thread -> deep MLP, 64KB total
    const uint4* c4 = (const uint4*)counts;
    uint4 L[4];
#pragma unroll
    for (int k = 0; k < 4; ++k) L[k] = c4[t * 4 + k];

    unsigned int local[16];
#pragma unroll
    for (int k = 0; k < 4; ++k) {
        local[k * 4 + 0] = L[k].x;
        local[k * 4 + 1] = L[k].y;
        local[k * 4 + 2] = L[k].z;
        local[k * 4 + 3] = L[k].w;
    }
    unsigned int sum = 0;
#pragma unroll
    for (int i = 0; i < 16; ++i) sum += local[i];
    lds[t] = sum;
    __syncthreads();
    for (int off = 1; off < 1024; off <<= 1) {
        unsigned int v = (t >= off) ? lds[t - off] : 0u;
        __syncthreads();
        lds[t] += v;
        __syncthreads();
    }
    unsigned int base = lds[t] - sum;  // exclusive base for this thread's 16 bins
#pragma unroll
    for (int i = 0; i < 16; ++i) {
        offsets[t * 16 + i] = base;
        cursor[t * 16 + i]  = base;
        base += local[i];
    }
    if (t == 1023) offsets[M_ROWS] = lds[1023];
}

// ---------------- phase 3: scatter (4 nnz/thread via int4/float4) ----------------
__global__ __launch_bounds__(256) void scatter_kernel(const int* __restrict__ idx,
                                                      const float* __restrict__ vals,
                                                      unsigned int* __restrict__ cursor,
                                                      int2* __restrict__ pairs) {
    const int i = blockIdx.x * 256 + threadIdx.x;          // 262144 threads
    const int4   r4 = ((const int4*)idx)[i];
    const int4   c4 = ((const int4*)(idx + NNZ_C))[i];
    const float4 v4 = ((const float4*)vals)[i];

    unsigned int p;
    p = atomicAdd(&cursor[r4.x], 1u); pairs[p] = make_int2(c4.x, __float_as_int(v4.x));
    p = atomicAdd(&cursor[r4.y], 1u); pairs[p] = make_int2(c4.y, __float_as_int(v4.y));
    p = atomicAdd(&cursor[r4.z], 1u); pairs[p] = make_int2(c4.z, __float_as_int(v4.z));
    p = atomicAdd(&cursor[r4.w], 1u); pairs[p] = make_int2(c4.w, __float_as_int(v4.w));
}

// ---------------- phase 4: wave-per-row SpMM (unchanged control) ----------------
__global__ __launch_bounds__(256) void spmm_csr_kernel(const unsigned int* __restrict__ offsets,
                                                       const int2* __restrict__ pairs,
                                                       const float* __restrict__ B,
                                                       float* __restrict__ out) {
    const int row  = blockIdx.x * 4 + (threadIdx.x >> 6);   // wave = row
    const int lane = threadIdx.x & 63;

    unsigned int beg = __builtin_amdgcn_readfirstlane(offsets[row]);
    unsigned int end = __builtin_amdgcn_readfirstlane(offsets[row + 1]);

    const float4* __restrict__ B4 = (const float4*)B;
    float4 acc = make_float4(0.f, 0.f, 0.f, 0.f);

    for (unsigned int base_p = beg; base_p < end; base_p += 64) {
        const unsigned int p = base_p + lane;
        int pc = 0, pv = 0;
        if (p < end) {
            int2 pr = pairs[p];
            pc = pr.x;
            pv = pr.y;
        }
#pragma unroll 8
        for (int j = 0; j < 64; ++j) {
            const int   c = __builtin_amdgcn_readlane(pc, j);
            const float v = __int_as_float(__builtin_amdgcn_readlane(pv, j));
            const float4 b = B4[(size_t)c * 64 + lane];                // 1KB/wave gather
            acc.x += v * b.x;
            acc.y += v * b.y;
            acc.z += v * b.z;
            acc.w += v * b.w;
        }
    }
    ((float4*)out)[(size_t)row * 64 + lane] = acc;  // single coalesced 1KB/wave store
}

// ---------------- fallback if workspace too small ----------------
__global__ __launch_bounds__(256) void spmm_atomic_kernel(
    const float* __restrict__ vals, const int* __restrict__ idx,
    const float* __restrict__ B, float* __restrict__ out) {
    const int wave = (int)(blockIdx.x * 4 + (threadIdx.x >> 6));
    const int lane = (int)(threadIdx.x & 63);
    if (wave >= NNZ_C) return;
    const int r = idx[wave];
    const int c = idx[NNZ_C + wave];
    const float v = vals[wave];
    const float* brow = B + (size_t)c * NCOL;
    float* orow = out + (size_t)r * NCOL;
#pragma unroll
    for (int k = 0; k < 4; ++k) {
        const int col = lane + 64 * k;
        atomicAdd(&orow[col], v * brow[col]);
    }
}

extern "C" void kernel_launch(void* const* d_in, const int* in_sizes, int n_in,
                              void* d_out, int out_size, void* d_ws, size_t ws_size,
                              hipStream_t stream) {
    const float* A_values  = (const float*)d_in[0];
    const int*   A_indices = (const int*)d_in[1];   // int32 (JAX x64 disabled), [2, NNZ]
    const float* B         = (const float*)d_in[2];
    float*       out       = (float*)d_out;

    const size_t OFFSETS_OFF = 0;                       // 16385 u32
    const size_t COUNTS_OFF  = 66560;                   // 16384 u32 (reused as cursor)
    const size_t PAIRS_OFF   = COUNTS_OFF + 65536;
    const size_t NEEDED      = PAIRS_OFF + (size_t)NNZ_C * 8;  // ~8.5 MB

    if (ws_size < NEEDED) {
        hipMemsetAsync(d_out, 0, (size_t)out_size * sizeof(float), stream);
        spmm_atomic_kernel<<<NNZ_C / 4, 256, 0, stream>>>(A_values, A_indices, B, out);
        return;
    }

    uint8_t* w = (uint8_t*)d_ws;
    unsigned int* offsets = (unsigned int*)(w + OFFSETS_OFF);
    unsigned int* counts  = (unsigned int*)(w + COUNTS_OFF);   // also cursor
    int2*         pairs   = (int2*)(w + PAIRS_OFF);

    hipMemsetAsync(counts, 0, M_ROWS * sizeof(unsigned int), stream);
    hist_kernel<<<NNZ_C / 4 / 256, 256, 0, stream>>>(A_indices, counts);
    scan_kernel<<<1, 1024, 0, stream>>>(counts, offsets, counts /*cursor*/);
    scatter_kernel<<<NNZ_C / 4 / 256, 256, 0, stream>>>(A_indices, A_values, counts /*cursor*/, pairs);
    spmm_csr_kernel<<<M_ROWS / 4, 256, 0, stream>>>(offsets, pairs, B, out);
}